// Round 9
// baseline (5680.708 us; speedup 1.0000x reference)
//
#include <hip/hip_runtime.h>
#include <stdint.h>

// Problem dims
#define Hh 256                 // hidden
#define Sd 128                 // batch (seq positions)
#define Nt 512                 // time steps per pass
#define NPASS 3
#define TSTEPS (NPASS*Nt)      // 1536
#define RBLK 16                // batch rows per chain
#define POIS 0x7F80u           // bf16 +inf: |h|<1 so never a real h value
#define LEAD 192               // max L0 lead over L1; with 16-step cadence <= 208 < 256

typedef float f32x4 __attribute__((ext_vector_type(4)));
typedef __bf16 bf16x8 __attribute__((ext_vector_type(8)));
typedef unsigned short u16x8 __attribute__((ext_vector_type(8)));
typedef unsigned long long ull;
typedef ull ull2 __attribute__((ext_vector_type(2)));

#define HBUF_ELEMS ((size_t)Nt*Sd*Hh)            // ushorts per layer h-ring
#define WPACK_OFF  (2ull*HBUF_ELEMS*2)           // 67,108,864 B
#define FLAGS_OFF  (WPACK_OFF + 2097152ull)      // +2MB packed weights

__device__ __forceinline__ unsigned short f2bf(float f) {
  unsigned u = __builtin_bit_cast(unsigned, f);
  u += 0x7FFFu + ((u >> 16) & 1u);               // RNE
  return (unsigned short)(u >> 16);
}
__device__ __forceinline__ ull pk4(float a, float b, float c, float d) {
  return (ull)f2bf(a) | ((ull)f2bf(b) << 16) | ((ull)f2bf(c) << 32) | ((ull)f2bf(d) << 48);
}
__device__ __forceinline__ bool hasPois(ull v) {
  return ((unsigned short)(v)       == (unsigned short)POIS) |
         ((unsigned short)(v >> 16) == (unsigned short)POIS) |
         ((unsigned short)(v >> 32) == (unsigned short)POIS) |
         ((unsigned short)(v >> 48) == (unsigned short)POIS);
}
// Relaxed agent-scope (cross-XCD coherent) helpers — no fences anywhere.
__device__ __forceinline__ ull ld8(const void* p) {
  return __hip_atomic_load((ull*)p, __ATOMIC_RELAXED, __HIP_MEMORY_SCOPE_AGENT);
}
__device__ __forceinline__ void st8c(void* p, ull v) {
  __hip_atomic_store((ull*)p, v, __ATOMIC_RELAXED, __HIP_MEMORY_SCOPE_AGENT);
}
__device__ __forceinline__ void poll2(const ull* p, ull& a0, ull& a1) {
  while (hasPois(a0) | hasPois(a1)) {
    __builtin_amdgcn_s_sleep(1);
    if (hasPois(a0)) a0 = ld8(p);
    if (hasPois(a1)) a1 = ld8(p + 1);
  }
}
// LDS-only barrier: orders ds ops without draining vmcnt (stores/prefetch
// loads stay in flight across it).
__device__ __forceinline__ void bar_lgkm() {
  __builtin_amdgcn_sched_barrier(0);
  asm volatile("s_waitcnt lgkmcnt(0)" ::: "memory");
  __builtin_amdgcn_s_barrier();
  __builtin_amdgcn_sched_barrier(0);
}

// ---------------- weight packing ----------------
// id = l<<16 | g2<<13 | w<<10 | kt<<6 | ln ; 8 bf16 per slot.
// value(j) = W.T[k = kt*32 + (ln>>4)*8 + j][col = (w>>1)*256 + g2*32 + (w&1)*16 + (ln&15)]
__global__ void pack_w(const float* __restrict__ Wih0, const float* __restrict__ Whh0,
                       const float* __restrict__ Wih1, const float* __restrict__ Whh1,
                       unsigned short* __restrict__ wpack) {
  int id = blockIdx.x * 256 + threadIdx.x;       // 131072 total
  int ln = id & 63;
  int kt = (id >> 6) & 15;
  int w  = (id >> 10) & 7;
  int g2 = (id >> 13) & 7;
  int l  = (id >> 16) & 1;
  int col = (w >> 1)*256 + g2*32 + (w & 1)*16 + (ln & 15);
  int k0 = kt*32 + (ln >> 4)*8;
  const float* Wih = l ? Wih1 : Wih0;
  const float* Whh = l ? Whh1 : Whh0;
  const float* src = (k0 < 256) ? (Wih + (size_t)col*256 + k0)
                                : (Whh + (size_t)col*256 + (k0 - 256));
  u16x8 v;
#pragma unroll
  for (int j = 0; j < 8; ++j) v[j] = f2bf(src[j]);
  *(u16x8*)(wpack + (size_t)id * 8) = v;
}

// ---------------- data[0] = x copy ----------------
__global__ void copy_x(const float* __restrict__ x, float* __restrict__ out) {
  int id = blockIdx.x * 256 + threadIdx.x;       // 4,194,304 float4s
  int n  = id >> 13;
  int s  = (id >> 6) & 127;
  int h4 = id & 63;
  const float4 v = *(const float4*)(x + ((size_t)n*Sd + s)*Hh + h4*4);
  *(float4*)(out + ((size_t)n*(Sd*4) + s*4)*Hh + h4*4) = v;
}

// ---------------- ring pre-poison ----------------
__global__ void poison_hbuf(unsigned int* __restrict__ p) {
  size_t i = (size_t)blockIdx.x * 256 + threadIdx.x;   // 4,194,304 x 16B = 64MB
  uint4 v = make_uint4(0x7F807F80u, 0x7F807F80u, 0x7F807F80u, 0x7F807F80u);
  *(uint4*)(p + i*4) = v;
}

// ---------------- persistent dual-chain LSTM ----------------
// 64 blocks x 512 threads. b: rgp=b&3 (chains rA=2rgp, rB=2rgp+1),
// g2=(b>>2)&7 (32 h-cols), l=(b>>5)&1. Two independent row-chains share one
// block's weights/barriers: every round advances BOTH chains one step, so
// per-round costs (MALL RT, convoy jitter, barriers) amortize 2x, and the
// early h-load window becomes a full round (> MALL RT).
__global__ void __launch_bounds__(512) lstm_persist(
    const float* __restrict__ x,
    const float* __restrict__ bih0, const float* __restrict__ bhh0,
    const float* __restrict__ bih1, const float* __restrict__ bhh1,
    const unsigned short* __restrict__ wpack,
    unsigned short* __restrict__ hbuf,
    unsigned int* __restrict__ prog,
    float* __restrict__ out)
{
  const int b = blockIdx.x;
  const int rgp = b & 3;
  const int g2 = (b >> 2) & 7;
  const int l = (b >> 5) & 1;
  const int tid = threadIdx.x;
  const int ln = tid & 63;
  const int w  = tid >> 6;                 // 0..7: q=w>>1 (gate quadrant), jt=w&1

  __shared__ __align__(16) unsigned short AinB[2][2][RBLK * 256]; // [chain][dbuf]
  __shared__ __align__(16) unsigned short Ah[2][RBLK * 256];      // [chain]
  __shared__ float gates[2][RBLK][132];                           // [chain][row][q*32+cc]

  // weight fragments: 16 ktiles x 4 VGPR = 64 VGPRs, SHARED by both chains
  bf16x8 B[16];
  {
    const unsigned short* base = wpack + ((size_t)((l*8 + g2)*8 + w)) * 8192 + (size_t)ln * 8;
#pragma unroll
    for (int kt = 0; kt < 16; ++kt) {
      u16x8 u = *(const u16x8*)(base + kt * 512);
      B[kt] = __builtin_bit_cast(bf16x8, u);
    }
  }

  // staging + cell identity: thread -> (row = tid>>5, 16B chunk / h-col = tid&31)
  const int srow = tid >> 5;               // 0..15
  const int cc   = tid & 31;               // 16B chunk (k) == h-col (cell)
  const int hcol = g2*32 + cc;             // global h col for cell
  int sC[2];                               // global seq row per chain
  sC[0] = (rgp*2    )*RBLK + srow;
  sC[1] = (rgp*2 + 1)*RBLK + srow;
  float bias[4];
  {
    const float* bi = l ? bih1 : bih0;
    const float* bh = l ? bhh1 : bhh0;
#pragma unroll
    for (int q = 0; q < 4; ++q) {
      int col = q*256 + g2*32 + cc;
      bias[q] = bi[col] + bh[col];
    }
  }
  float cst[2] = {0.f, 0.f};

  // MFMA fragment addressing (16B-granular XOR swizzle, matches staging swizzle)
  const int row_f = ln & 15;
  const int kg16  = (ln >> 4) * 16;
  const int swr   = (row_f & 7) << 4;
  const int stAddr = srow*512 + ((cc*16) ^ ((srow & 7) << 4));

  const unsigned short* hbufL0 = hbuf;
  unsigned short* hbufSelf = hbuf + (size_t)l * HBUF_ELEMS;

  // per-chain pipeline registers
  float4 pxa[2], pxb[2];                   // L0 Ain sources (fp32)
  ull pa[2] = {0,0}, pb[2] = {0,0};        // L1 Ain sources (bf16)
  ull hpa[2] = {0,0}, hpb[2] = {0,0};      // early-issued h loads

#define MFMA4(BUF, BOFF, A0, A1)                                                    \
  {                                                                                 \
    _Pragma("unroll")                                                               \
    for (int kt = 0; kt < 8; kt += 2) {                                             \
      int off0 = row_f*512 + (( kt     *64 + kg16) ^ swr);                          \
      int off1 = row_f*512 + (((kt + 1)*64 + kg16) ^ swr);                          \
      u16x8 a0 = *(const u16x8*)((const char*)(BUF) + off0);                        \
      u16x8 a1 = *(const u16x8*)((const char*)(BUF) + off1);                        \
      A0 = __builtin_amdgcn_mfma_f32_16x16x32_bf16(                                 \
               __builtin_bit_cast(bf16x8, a0), B[BOFF + kt],     A0, 0,0,0);        \
      A1 = __builtin_amdgcn_mfma_f32_16x16x32_bf16(                                 \
               __builtin_bit_cast(bf16x8, a1), B[BOFF + kt + 1], A1, 0,0,0);        \
    }                                                                               \
  }

  f32x4 acc0[2], acc1[2];

  // ---- prologue: stage Ain_c(0), prefetch Ain_c(1), MFMA input-part(0) ----
#pragma unroll
  for (int c = 0; c < 2; ++c) {
    if (l == 1) {
      const ull* ip = (const ull*)(hbufL0 + (size_t)sC[c]*Hh + cc*8);
      ull a0 = ld8(ip), a1 = ld8(ip + 1);
      poll2(ip, a0, a1);
      ull2 v = {a0, a1}; *(ull2*)((char*)AinB[c][0] + stAddr) = v;
    } else {
      const float* xb = x + (size_t)sC[c]*Hh + cc*8;
      float4 v0 = *(const float4*)(xb), v1 = *(const float4*)(xb + 4);
      ull2 v = {pk4(v0.x, v0.y, v0.z, v0.w), pk4(v1.x, v1.y, v1.z, v1.w)};
      *(ull2*)((char*)AinB[c][0] + stAddr) = v;
    }
    // prefetch Ain_c(1)
    if (l == 1) {
      const ull* ip = (const ull*)(hbufL0 + ((size_t)1*Sd + sC[c])*Hh + cc*8);
      pa[c] = ld8(ip); pb[c] = ld8(ip + 1);
    } else {
      const float* xb = x + ((size_t)1*Sd + sC[c])*Hh + cc*8;
      pxa[c] = *(const float4*)(xb);
      pxb[c] = *(const float4*)(xb + 4);
    }
  }
  __syncthreads();
#pragma unroll
  for (int c = 0; c < 2; ++c) {
    acc0[c] = (f32x4){0.f,0.f,0.f,0.f};
    acc1[c] = (f32x4){0.f,0.f,0.f,0.f};
    MFMA4(AinB[c][0], 0, acc0[c], acc1[c])
  }

  for (int T = 0; T < TSTEPS; ++T) {
    const int p = T >> 9;
    const int t = T & 511;

    // ===== phase 1: stage Ah_c = h_c(T-1) (early loads issued last round;
    //               window = full round >= MALL RT, so check usually passes) =====
#pragma unroll
    for (int c = 0; c < 2; ++c) {
      if (T > 0) {
        const ull* ap = (const ull*)(hbufSelf + ((size_t)((T - 1) & 511)*Sd + sC[c])*Hh + cc*8);
        ull a0 = hpa[c], a1 = hpb[c];
        while (hasPois(a0) | hasPois(a1)) {
          if (hasPois(a0)) a0 = ld8(ap);
          if (hasPois(a1)) a1 = ld8(ap + 1);
        }
        ull2 v2 = {a0, a1};
        *(ull2*)((char*)Ah[c] + stAddr) = v2;
      } else {
        ull2 v2 = {0ull, 0ull};
        *(ull2*)((char*)Ah[c] + stAddr) = v2;
      }
    }
    // Ain_c(T+1) from prefetch regs -> LDS (other buffer)
    if (T + 1 < TSTEPS) {
#pragma unroll
      for (int c = 0; c < 2; ++c) {
        const int buf = (T + 1) & 1;
        if (l == 1) {
          ull a0 = pa[c], a1 = pb[c];
          if (hasPois(a0) | hasPois(a1)) {
            const ull* ip = (const ull*)(hbufL0 + ((size_t)((T + 1) & 511)*Sd + sC[c])*Hh + cc*8);
            poll2(ip, a0, a1);
          }
          ull2 v = {a0, a1}; *(ull2*)((char*)AinB[c][buf] + stAddr) = v;
        } else {
          ull2 v = {pk4(pxa[c].x, pxa[c].y, pxa[c].z, pxa[c].w),
                    pk4(pxb[c].x, pxb[c].y, pxb[c].z, pxb[c].w)};
          *(ull2*)((char*)AinB[c][buf] + stAddr) = v;
        }
      }
    }
    // L0 lead throttle, every 16 steps (both chains' flags)
    if (l == 0 && (T & 15) == 0 && tid < 16) {
      int need = T - LEAD;
      if (need > 0) {
        unsigned int* fl = prog + (rgp*2 + (tid >> 3))*8 + (tid & 7);
        while ((int)__hip_atomic_load(fl, __ATOMIC_RELAXED, __HIP_MEMORY_SCOPE_AGENT) < need)
          __builtin_amdgcn_s_sleep(1);
      }
    }
    bar_lgkm();                                         // barrier 1 (LDS-only)

    // ===== phase 3: hidden-part MFMAs + gates -> LDS =====
    {
      const int colb = (w >> 1)*32 + (w & 1)*16 + (ln & 15);
      const int rowb = (ln >> 4)*4;
#pragma unroll
      for (int c = 0; c < 2; ++c) {
        if (T > 0) MFMA4(Ah[c], 8, acc0[c], acc1[c])
#pragma unroll
        for (int j = 0; j < 4; ++j)
          gates[c][rowb + j][colb] = acc0[c][j] + acc1[c][j];
      }
    }
    bar_lgkm();                                         // barrier 2 (LDS-only)

    // ===== phase 5: LSTM cells; packed coherent stores =====
#pragma unroll
    for (int c = 0; c < 2; ++c) {
      float G0 = gates[c][srow][cc]      + bias[0];
      float G1 = gates[c][srow][32 + cc] + bias[1];
      float G2 = gates[c][srow][64 + cc] + bias[2];
      float G3 = gates[c][srow][96 + cc] + bias[3];
      float gi = 1.f/(1.f + __expf(-G0));
      float gf = 1.f/(1.f + __expf(-G1));
      float gg = 1.f - 2.f/(1.f + __expf(2.f*G2));
      float go = 1.f/(1.f + __expf(-G3));
      cst[c] = gf*cst[c] + gi*gg;
      float th = 1.f - 2.f/(1.f + __expf(2.f*cst[c]));
      float hv = go*th;
      float h1 = __shfl_down(hv, 1);
      float h2 = __shfl_down(hv, 2);
      float h3 = __shfl_down(hv, 3);
      if ((cc & 3) == 0) {
        st8c(hbufSelf + ((size_t)t*Sd + sC[c])*Hh + hcol, pk4(hv, h1, h2, h3));
        // re-poison slot reused 256 steps from now (all lag bounds < 256)
        st8c(hbufSelf + ((size_t)((T + 256) & 511)*Sd + sC[c])*Hh + hcol,
             0x7F807F807F807F80ull);
      }
      if (l == 1 && (cc & 1) == 0) {
        ull o01 = ((ull)__builtin_bit_cast(unsigned, hv))
                | ((ull)__builtin_bit_cast(unsigned, h1) << 32);
        st8c(out + ((size_t)t*(Sd*4) + sC[c]*4 + (p + 1))*Hh + hcol, o01);
      }
    }
    // flag publish (no drain — out-slack >= 300 steps)
    if (l == 1 && (T & 15) == 15 && tid == 0) {
      __hip_atomic_store(prog + (rgp*2    )*8 + g2, (unsigned)(T + 1),
                         __ATOMIC_RELAXED, __HIP_MEMORY_SCOPE_AGENT);
      __hip_atomic_store(prog + (rgp*2 + 1)*8 + g2, (unsigned)(T + 1),
                         __ATOMIC_RELAXED, __HIP_MEMORY_SCOPE_AGENT);
    }

    // ===== phase 6: issue next-round loads, then input-part MFMAs of T+1 =====
#pragma unroll
    for (int c = 0; c < 2; ++c) {
      if (T + 2 < TSTEPS) {                       // prefetch Ain_c(T+2)
        const int t2 = (T + 2) & 511, p2 = (T + 2) >> 9;
        if (l == 1) {
          const ull* ip = (const ull*)(hbufL0 + ((size_t)t2*Sd + sC[c])*Hh + cc*8);
          pa[c] = ld8(ip); pb[c] = ld8(ip + 1);
        } else if (p2 == 0) {
          const float* xb = x + ((size_t)t2*Sd + sC[c])*Hh + cc*8;
          pxa[c] = *(const float4*)(xb);
          pxb[c] = *(const float4*)(xb + 4);
        } else {
          const float* ob = out + ((size_t)t2*(Sd*4) + sC[c]*4 + p2)*Hh + cc*8;
          pxa[c] = *(const float4*)(ob);
          pxb[c] = *(const float4*)(ob + 4);
        }
      }
      if (T + 1 < TSTEPS) {                       // early h_c(T) loads
        const ull* ap = (const ull*)(hbufSelf + ((size_t)(T & 511)*Sd + sC[c])*Hh + cc*8);
        hpa[c] = ld8(ap);
        hpb[c] = ld8(ap + 1);
      }
    }
#pragma unroll
    for (int c = 0; c < 2; ++c) {
      acc0[c] = (f32x4){0.f,0.f,0.f,0.f};
      acc1[c] = (f32x4){0.f,0.f,0.f,0.f};
      if (T + 1 < TSTEPS) MFMA4(AinB[c][(T + 1) & 1], 0, acc0[c], acc1[c])
    }
  }
}

extern "C" void kernel_launch(void* const* d_in, const int* in_sizes, int n_in,
                              void* d_out, int out_size, void* d_ws, size_t ws_size,
                              hipStream_t stream) {
  const float* x    = (const float*)d_in[0];
  const float* Wih0 = (const float*)d_in[1];
  const float* Whh0 = (const float*)d_in[2];
  const float* bih0 = (const float*)d_in[3];
  const float* bhh0 = (const float*)d_in[4];
  const float* Wih1 = (const float*)d_in[5];
  const float* Whh1 = (const float*)d_in[6];
  const float* bih1 = (const float*)d_in[7];
  const float* bhh1 = (const float*)d_in[8];
  float* out = (float*)d_out;
  char* ws = (char*)d_ws;

  if (ws_size < FLAGS_OFF + 4096) return;  // need ~69 MB scratch

  unsigned short* hbuf  = (unsigned short*)ws;
  unsigned short* wpack = (unsigned short*)(ws + WPACK_OFF);
  unsigned int*   prog  = (unsigned int*)(ws + FLAGS_OFF);

  (void)hipMemsetAsync(prog, 0, 1024, stream);
  hipLaunchKernelGGL(poison_hbuf, dim3(16384), dim3(256), 0, stream, (unsigned int*)hbuf);
  hipLaunchKernelGGL(pack_w, dim3(512), dim3(256), 0, stream, Wih0, Whh0, Wih1, Whh1, wpack);
  hipLaunchKernelGGL(copy_x, dim3(16384), dim3(256), 0, stream, x, out);
  hipLaunchKernelGGL(lstm_persist, dim3(64), dim3(512), 0, stream,
                     x, bih0, bhh0, bih1, bhh1, wpack, hbuf, prog, out);
}

// Round 10
// 3825.621 us; speedup vs baseline: 1.4849x; 1.4849x over previous
//
#include <hip/hip_runtime.h>
#include <stdint.h>

// Problem dims
#define Hh 256                 // hidden
#define Sd 128                 // batch (seq positions)
#define Nt 512                 // time steps per pass
#define NPASS 3
#define TSTEPS (NPASS*Nt)      // 1536
#define RBLK 16                // batch rows per block
#define POIS 0x7F80u           // bf16 +inf: |h|<1 so never a real h value
#define LEAD 192               // max L0 lead over L1; with 16-step cadence <= 208 < 256

typedef float f32x4 __attribute__((ext_vector_type(4)));
typedef __bf16 bf16x8 __attribute__((ext_vector_type(8)));
typedef unsigned short u16x8 __attribute__((ext_vector_type(8)));
typedef unsigned long long ull;
typedef ull ull2 __attribute__((ext_vector_type(2)));

#define HBUF_ELEMS ((size_t)Nt*Sd*Hh)            // ushorts per layer h-ring
#define WPACK_OFF  (2ull*HBUF_ELEMS*2)           // 67,108,864 B
#define FLAGS_OFF  (WPACK_OFF + 2097152ull)      // +2MB packed weights

__device__ __forceinline__ unsigned short f2bf(float f) {
  unsigned u = __builtin_bit_cast(unsigned, f);
  u += 0x7FFFu + ((u >> 16) & 1u);               // RNE
  return (unsigned short)(u >> 16);
}
__device__ __forceinline__ ull pk4(float a, float b, float c, float d) {
  return (ull)f2bf(a) | ((ull)f2bf(b) << 16) | ((ull)f2bf(c) << 32) | ((ull)f2bf(d) << 48);
}
__device__ __forceinline__ bool hasPois(ull v) {
  return ((unsigned short)(v)       == (unsigned short)POIS) |
         ((unsigned short)(v >> 16) == (unsigned short)POIS) |
         ((unsigned short)(v >> 32) == (unsigned short)POIS) |
         ((unsigned short)(v >> 48) == (unsigned short)POIS);
}
// Relaxed agent-scope (cross-XCD coherent) helpers — no fences anywhere.
__device__ __forceinline__ ull ld8(const void* p) {
  return __hip_atomic_load((ull*)p, __ATOMIC_RELAXED, __HIP_MEMORY_SCOPE_AGENT);
}
__device__ __forceinline__ void st8c(void* p, ull v) {
  __hip_atomic_store((ull*)p, v, __ATOMIC_RELAXED, __HIP_MEMORY_SCOPE_AGENT);
}
// Joint poll over 4 chunks: all stale chunks retried per round trip.
__device__ __forceinline__ void poll4(const ull* p, ull a[4]) {
  for (;;) {
    bool st = hasPois(a[0]) | hasPois(a[1]) | hasPois(a[2]) | hasPois(a[3]);
    if (!st) return;
#pragma unroll
    for (int u = 0; u < 4; ++u)
      if (hasPois(a[u])) a[u] = ld8(p + u);
  }
}
// LDS-only barrier: orders ds ops without draining vmcnt (stores/prefetch
// loads stay in flight across it).
__device__ __forceinline__ void bar_lgkm() {
  __builtin_amdgcn_sched_barrier(0);
  asm volatile("s_waitcnt lgkmcnt(0)" ::: "memory");
  __builtin_amdgcn_s_barrier();
  __builtin_amdgcn_sched_barrier(0);
}

// ---------------- weight packing (unchanged, verified) ----------------
// id = l<<16 | g2<<13 | w'<<10 | kt<<6 | ln ; 8 bf16 per slot.
// value(j) = W.T[k = kt*32 + (ln>>4)*8 + j][col = (w'>>1)*256 + g2*32 + (w'&1)*16 + (ln&15)]
__global__ void pack_w(const float* __restrict__ Wih0, const float* __restrict__ Whh0,
                       const float* __restrict__ Wih1, const float* __restrict__ Whh1,
                       unsigned short* __restrict__ wpack) {
  int id = blockIdx.x * 256 + threadIdx.x;       // 131072 total
  int ln = id & 63;
  int kt = (id >> 6) & 15;
  int w  = (id >> 10) & 7;
  int g2 = (id >> 13) & 7;
  int l  = (id >> 16) & 1;
  int col = (w >> 1)*256 + g2*32 + (w & 1)*16 + (ln & 15);
  int k0 = kt*32 + (ln >> 4)*8;
  const float* Wih = l ? Wih1 : Wih0;
  const float* Whh = l ? Whh1 : Whh0;
  const float* src = (k0 < 256) ? (Wih + (size_t)col*256 + k0)
                                : (Whh + (size_t)col*256 + (k0 - 256));
  u16x8 v;
#pragma unroll
  for (int j = 0; j < 8; ++j) v[j] = f2bf(src[j]);
  *(u16x8*)(wpack + (size_t)id * 8) = v;
}

// ---------------- data[0] = x copy ----------------
__global__ void copy_x(const float* __restrict__ x, float* __restrict__ out) {
  int id = blockIdx.x * 256 + threadIdx.x;       // 4,194,304 float4s
  int n  = id >> 13;
  int s  = (id >> 6) & 127;
  int h4 = id & 63;
  const float4 v = *(const float4*)(x + ((size_t)n*Sd + s)*Hh + h4*4);
  *(float4*)(out + ((size_t)n*(Sd*4) + s*4)*Hh + h4*4) = v;
}

// ---------------- ring pre-poison ----------------
__global__ void poison_hbuf(unsigned int* __restrict__ p) {
  size_t i = (size_t)blockIdx.x * 256 + threadIdx.x;   // 4,194,304 x 16B = 64MB
  uint4 v = make_uint4(0x7F807F80u, 0x7F807F80u, 0x7F807F80u, 0x7F807F80u);
  *(uint4*)(p + i*4) = v;
}

// ---------------- persistent pipelined LSTM ----------------
// 128 blocks x 256 threads (4 waves). b: r=b&7, g2=(b>>3)&7 (32 h-cols), l=(b>>6)&1.
// Each wave owns 2 col-tiles (gate quadrant w, subtiles jt=0,1): halves the
// per-CU LDS A-broadcast vs 8 waves x 1 tile (each a-frag feeds 2 MFMAs).
__global__ void __launch_bounds__(256, 1) lstm_persist(
    const float* __restrict__ x,
    const float* __restrict__ bih0, const float* __restrict__ bhh0,
    const float* __restrict__ bih1, const float* __restrict__ bhh1,
    const unsigned short* __restrict__ wpack,
    unsigned short* __restrict__ hbuf,
    unsigned int* __restrict__ prog,
    float* __restrict__ out)
{
  const int b = blockIdx.x;
  const int r = b & 7;
  const int g2 = (b >> 3) & 7;
  const int l = (b >> 6) & 1;
  const int tid = threadIdx.x;
  const int ln = tid & 63;
  const int w  = tid >> 6;                 // wave 0..3 = gate quadrant q

  __shared__ __align__(16) unsigned short AinB[2][RBLK * 256]; // input operand, dbuf
  __shared__ __align__(16) unsigned short Ah[RBLK * 256];      // hidden operand
  __shared__ float gates[RBLK][132];                           // [row][q*32 + cc], +4 pad

  // weight fragments: 2 tiles x 16 ktiles x 4 VGPR = 128 VGPRs, resident
  bf16x8 B0[16], B1[16];
  {
    const unsigned short* base0 = wpack + ((size_t)((l*8 + g2)*8 + 2*w    )) * 8192 + (size_t)ln * 8;
    const unsigned short* base1 = wpack + ((size_t)((l*8 + g2)*8 + 2*w + 1)) * 8192 + (size_t)ln * 8;
#pragma unroll
    for (int kt = 0; kt < 16; ++kt) {
      u16x8 u0 = *(const u16x8*)(base0 + kt * 512);
      u16x8 u1 = *(const u16x8*)(base1 + kt * 512);
      B0[kt] = __builtin_bit_cast(bf16x8, u0);
      B1[kt] = __builtin_bit_cast(bf16x8, u1);
    }
  }

  // staging + cell identity: thread -> (row = tid>>4, 32B chunk-pair / 2 h-cols)
  const int srow = tid >> 4;               // 0..15
  const int cp   = tid & 15;               // chunk-pair: chunks 2cp, 2cp+1; h-cols cp, cp+16
  const int s    = r*RBLK + srow;          // global seq row
  const int hc0  = cp;                     // local h col (first)
  const int hcol0 = g2*32 + cp;            // global h cols cp and cp+16
  float bias0[4], bias1[4];
  {
    const float* bi = l ? bih1 : bih0;
    const float* bh = l ? bhh1 : bhh0;
#pragma unroll
    for (int q = 0; q < 4; ++q) {
      int col = q*256 + g2*32 + cp;
      bias0[q] = bi[col] + bh[col];
      bias1[q] = bi[col + 16] + bh[col + 16];
    }
  }
  float cst0 = 0.f, cst1 = 0.f;

  // MFMA fragment addressing (16B-granular XOR swizzle, matches staging swizzle)
  const int row_f = ln & 15;
  const int kg16  = (ln >> 4) * 16;
  const int swr   = (row_f & 7) << 4;
  const int sw    = (srow & 7) << 4;
  const int stAddr0 = srow*512 + ((cp*32)      ^ sw);
  const int stAddr1 = srow*512 + ((cp*32 + 16) ^ sw);

  unsigned int* flagL1 = prog + r*8;           // 8 L1 publishers per rowblock
  unsigned int* myFlag = prog + r*8 + g2;
  const unsigned short* hbufL0 = hbuf;
  unsigned short* hbufSelf = hbuf + (size_t)l * HBUF_ELEMS;

  // ---- pipeline registers ----
  float4 px[4];                            // L0 Ain sources (x fp32 / out fp32)
  ull pa[4] = {0,0,0,0};                   // L1 Ain source (hbufL0 bf16)
  ull hp[4] = {0,0,0,0};                   // early-issued h loads

  auto writeAin = [&](int buf, ull v0, ull v1, ull v2, ull v3) {
    ull2 a = {v0, v1}; *(ull2*)((char*)AinB[buf] + stAddr0) = a;
    ull2 c = {v2, v3}; *(ull2*)((char*)AinB[buf] + stAddr1) = c;
  };
  // issue global loads for Ain(T2) into regs — NO wait here
  auto prefetchAin = [&](int T2) {
    const int t2 = T2 & 511, p2 = T2 >> 9;
    if (l == 1) {
      const ull* ip = (const ull*)(hbufL0 + ((size_t)t2*Sd + s)*Hh + cp*16);
#pragma unroll
      for (int u = 0; u < 4; ++u) pa[u] = ld8(ip + u);
    } else if (p2 == 0) {
      const float* xb = x + ((size_t)t2*Sd + s)*Hh + cp*16;
#pragma unroll
      for (int u = 0; u < 4; ++u) px[u] = *(const float4*)(xb + 4*u);
    } else {
      // data[p2]: written by L1 >=300 steps before L0 reads it (flag-guarded);
      // addresses read exactly once -> no staleness hazard.
      const float* ob = out + ((size_t)t2*(Sd*4) + s*4 + p2)*Hh + cp*16;
#pragma unroll
      for (int u = 0; u < 4; ++u) px[u] = *(const float4*)(ob + 4*u);
    }
  };
  // convert + LDS-write the prefetched Ain(T1); L1 verifies poison here
  auto consumeAin = [&](int T1) {
    const int buf = T1 & 1;
    if (l == 1) {
      if (hasPois(pa[0]) | hasPois(pa[1]) | hasPois(pa[2]) | hasPois(pa[3])) {
        const ull* ip = (const ull*)(hbufL0 + ((size_t)(T1 & 511)*Sd + s)*Hh + cp*16);
        poll4(ip, pa);
      }
      writeAin(buf, pa[0], pa[1], pa[2], pa[3]);
    } else {
      writeAin(buf,
               pk4(px[0].x, px[0].y, px[0].z, px[0].w),
               pk4(px[1].x, px[1].y, px[1].z, px[1].w),
               pk4(px[2].x, px[2].y, px[2].z, px[2].w),
               pk4(px[3].x, px[3].y, px[3].z, px[3].w));
    }
  };

  f32x4 acc00, acc01, acc10, acc11;        // [tile jt][chain]

#define MFMA8(BUF, BOFF)                                                            \
  {                                                                                 \
    _Pragma("unroll")                                                               \
    for (int kt = 0; kt < 8; kt += 2) {                                             \
      int off0 = row_f*512 + (( kt     *64 + kg16) ^ swr);                          \
      int off1 = row_f*512 + (((kt + 1)*64 + kg16) ^ swr);                          \
      u16x8 a0 = *(const u16x8*)((const char*)(BUF) + off0);                        \
      u16x8 a1 = *(const u16x8*)((const char*)(BUF) + off1);                        \
      bf16x8 af0 = __builtin_bit_cast(bf16x8, a0);                                  \
      bf16x8 af1 = __builtin_bit_cast(bf16x8, a1);                                  \
      acc00 = __builtin_amdgcn_mfma_f32_16x16x32_bf16(af0, B0[BOFF + kt],     acc00, 0,0,0); \
      acc10 = __builtin_amdgcn_mfma_f32_16x16x32_bf16(af0, B1[BOFF + kt],     acc10, 0,0,0); \
      acc01 = __builtin_amdgcn_mfma_f32_16x16x32_bf16(af1, B0[BOFF + kt + 1], acc01, 0,0,0); \
      acc11 = __builtin_amdgcn_mfma_f32_16x16x32_bf16(af1, B1[BOFF + kt + 1], acc11, 0,0,0); \
    }                                                                               \
  }

  // ---- prologue: stage Ain(0) directly, prefetch Ain(1), MFMA input-part(0) ----
  acc00 = acc01 = acc10 = acc11 = (f32x4){0.f,0.f,0.f,0.f};
  if (l == 1) {
    const ull* ip = (const ull*)(hbufL0 + (size_t)s*Hh + cp*16);
    ull a[4];
#pragma unroll
    for (int u = 0; u < 4; ++u) a[u] = ld8(ip + u);
    poll4(ip, a);
    writeAin(0, a[0], a[1], a[2], a[3]);
  } else {
    const float* xb = x + (size_t)s*Hh + cp*16;
    float4 v0 = *(const float4*)(xb),     v1 = *(const float4*)(xb + 4);
    float4 v2 = *(const float4*)(xb + 8), v3 = *(const float4*)(xb + 12);
    writeAin(0, pk4(v0.x, v0.y, v0.z, v0.w), pk4(v1.x, v1.y, v1.z, v1.w),
                pk4(v2.x, v2.y, v2.z, v2.w), pk4(v3.x, v3.y, v3.z, v3.w));
  }
  prefetchAin(1);
  __syncthreads();
  MFMA8(AinB[0], 0)

  for (int T = 0; T < TSTEPS; ++T) {
    const int p = T >> 9;
    const int t = T & 511;

    // ===== 1: stage Ah = h(T-1) (early loads issued last iter; check + retry) =====
    if (T > 0) {
      const ull* ap = (const ull*)(hbufSelf + ((size_t)((T - 1) & 511)*Sd + s)*Hh + cp*16);
      poll4(ap, hp);
      ull2 v0 = {hp[0], hp[1]}; *(ull2*)((char*)Ah + stAddr0) = v0;
      ull2 v1 = {hp[2], hp[3]}; *(ull2*)((char*)Ah + stAddr1) = v1;
    } else {
      ull2 z = {0ull, 0ull};
      *(ull2*)((char*)Ah + stAddr0) = z;
      *(ull2*)((char*)Ah + stAddr1) = z;
    }
    // ===== 2: Ain(T+1) from prefetch regs -> LDS (other buffer) =====
    if (T + 1 < TSTEPS) consumeAin(T + 1);
    // ===== 3: L0 lead throttle, every 16 steps =====
    if (l == 0 && (T & 15) == 0 && tid < 8) {
      int need = T - LEAD;
      if (need > 0)
        while ((int)__hip_atomic_load(flagL1 + tid, __ATOMIC_RELAXED, __HIP_MEMORY_SCOPE_AGENT) < need)
          __builtin_amdgcn_s_sleep(1);
    }
    bar_lgkm();                                         // barrier 1 (LDS-only)

    // ===== 4: hidden-part MFMAs (acc already holds input-part of T) =====
    if (T > 0) MFMA8(Ah, 8)

    // gates -> LDS (C layout: col=lane&15, row=(lane>>4)*4+j)
    {
      const int colb = w*32 + (ln & 15);
      const int rowb = (ln >> 4)*4;
#pragma unroll
      for (int j = 0; j < 4; ++j) {
        gates[rowb + j][colb]      = acc00[j] + acc01[j];
        gates[rowb + j][colb + 16] = acc10[j] + acc11[j];
      }
    }
    bar_lgkm();                                         // barrier 2 (LDS-only)

    // ===== 5: LSTM cells (2 per thread); packed coherent stores =====
    {
      float hv0, hv1;
      {
        float G0 = gates[srow][hc0]      + bias0[0];
        float G1 = gates[srow][32 + hc0] + bias0[1];
        float G2 = gates[srow][64 + hc0] + bias0[2];
        float G3 = gates[srow][96 + hc0] + bias0[3];
        float gi = 1.f/(1.f + __expf(-G0));
        float gf = 1.f/(1.f + __expf(-G1));
        float gg = 1.f - 2.f/(1.f + __expf(2.f*G2));
        float go = 1.f/(1.f + __expf(-G3));
        cst0 = gf*cst0 + gi*gg;
        hv0 = go*(1.f - 2.f/(1.f + __expf(2.f*cst0)));
      }
      {
        float G0 = gates[srow][16 + hc0]  + bias1[0];
        float G1 = gates[srow][48 + hc0]  + bias1[1];
        float G2 = gates[srow][80 + hc0]  + bias1[2];
        float G3 = gates[srow][112 + hc0] + bias1[3];
        float gi = 1.f/(1.f + __expf(-G0));
        float gf = 1.f/(1.f + __expf(-G1));
        float gg = 1.f - 2.f/(1.f + __expf(2.f*G2));
        float go = 1.f/(1.f + __expf(-G3));
        cst1 = gf*cst1 + gi*gg;
        hv1 = go*(1.f - 2.f/(1.f + __expf(2.f*cst1)));
      }
      float a1 = __shfl_down(hv0, 1), a2 = __shfl_down(hv0, 2), a3 = __shfl_down(hv0, 3);
      float b1 = __shfl_down(hv1, 1), b2 = __shfl_down(hv1, 2), b3 = __shfl_down(hv1, 3);
      if ((cp & 3) == 0) {
        unsigned short* hb = hbufSelf + ((size_t)t*Sd + s)*Hh + hcol0;
        unsigned short* pb = hbufSelf + ((size_t)((T + 256) & 511)*Sd + s)*Hh + hcol0;
        st8c(hb,      pk4(hv0, a1, a2, a3));
        st8c(hb + 16, pk4(hv1, b1, b2, b3));
        // re-poison slot reused 256 steps from now (all lag bounds < 256)
        st8c(pb,      0x7F807F807F807F80ull);
        st8c(pb + 16, 0x7F807F807F807F80ull);
      }
      if (l == 1 && (cp & 1) == 0) {
        float* ob = out + ((size_t)t*(Sd*4) + s*4 + (p + 1))*Hh + hcol0;
        ull o0 = ((ull)__builtin_bit_cast(unsigned, hv0))
               | ((ull)__builtin_bit_cast(unsigned, a1) << 32);
        ull o1 = ((ull)__builtin_bit_cast(unsigned, hv1))
               | ((ull)__builtin_bit_cast(unsigned, b1) << 32);
        st8c(ob,      o0);
        st8c(ob + 16, o1);
      }
    }
    // ===== 6: flag publish (no drain — out-slack >=300 steps) =====
    if (l == 1 && (T & 15) == 15 && tid == 0)
      __hip_atomic_store(myFlag, (unsigned)(T + 1), __ATOMIC_RELAXED, __HIP_MEMORY_SCOPE_AGENT);
    // ===== 7: issue Ain(T+2) prefetch + early h(T) loads =====
    if (T + 2 < TSTEPS) prefetchAin(T + 2);
    if (T + 1 < TSTEPS) {
      const ull* ap = (const ull*)(hbufSelf + ((size_t)(T & 511)*Sd + s)*Hh + cp*16);
#pragma unroll
      for (int u = 0; u < 4; ++u) hp[u] = ld8(ap + u);
    }
    // ===== 8: input-part MFMAs of step T+1 (covers the h(T) exchange hop) =====
    acc00 = acc01 = acc10 = acc11 = (f32x4){0.f,0.f,0.f,0.f};
    if (T + 1 < TSTEPS) MFMA8(AinB[(T + 1) & 1], 0)
  }
}

extern "C" void kernel_launch(void* const* d_in, const int* in_sizes, int n_in,
                              void* d_out, int out_size, void* d_ws, size_t ws_size,
                              hipStream_t stream) {
  const float* x    = (const float*)d_in[0];
  const float* Wih0 = (const float*)d_in[1];
  const float* Whh0 = (const float*)d_in[2];
  const float* bih0 = (const float*)d_in[3];
  const float* bhh0 = (const float*)d_in[4];
  const float* Wih1 = (const float*)d_in[5];
  const float* Whh1 = (const float*)d_in[6];
  const float* bih1 = (const float*)d_in[7];
  const float* bhh1 = (const float*)d_in[8];
  float* out = (float*)d_out;
  char* ws = (char*)d_ws;

  if (ws_size < FLAGS_OFF + 4096) return;  // need ~69 MB scratch

  unsigned short* hbuf  = (unsigned short*)ws;
  unsigned short* wpack = (unsigned short*)(ws + WPACK_OFF);
  unsigned int*   prog  = (unsigned int*)(ws + FLAGS_OFF);

  (void)hipMemsetAsync(prog, 0, 1024, stream);
  hipLaunchKernelGGL(poison_hbuf, dim3(16384), dim3(256), 0, stream, (unsigned int*)hbuf);
  hipLaunchKernelGGL(pack_w, dim3(512), dim3(256), 0, stream, Wih0, Whh0, Wih1, Whh1, wpack);
  hipLaunchKernelGGL(copy_x, dim3(16384), dim3(256), 0, stream, x, out);
  hipLaunchKernelGGL(lstm_persist, dim3(128), dim3(256), 0, stream,
                     x, bih0, bhh0, bih1, bhh1, wpack, hbuf, prog, out);
}